// Round 11
// baseline (2599.588 us; speedup 1.0000x reference)
//
#include <hip/hip_runtime.h>
#include <hip/hip_bf16.h>

typedef unsigned short u16;
typedef unsigned int u32;
typedef unsigned long long u64;
typedef __bf16 bf16x8 __attribute__((ext_vector_type(8)));
typedef float f32x4 __attribute__((ext_vector_type(4)));

#define NB 64
#define NT 128
#define NF 1024
#define NH 1024
#define NK 2048   // F+H
#define NG 4096   // 4H
#define NBH (NB * NH)

// LDS: W 128 KiB + zsx[2][2][64][17] + zsh[2][64][17] + stamps
#define W_LDS_BYTES 131072
#define ZSX_BYTES (2 * 2 * 64 * 17 * 4)   // 17408
#define ZSH_BYTES (2 * 64 * 17 * 4)       // 8704
#define ST_BYTES 64
#define SMEM_BYTES (W_LDS_BYTES + ZSX_BYTES + ZSH_BYTES + ST_BYTES)  // 157248

// stamp slots (all monotonic, single-writer, init 0):
// st[0..1]=xs_w  st[2..3]=xs_a  st[4..5]=hs_w  st[6..7]=hs_a  st[8..9]=pw
// st[10]=rendezvous broadcast (wave 6)
__device__ __forceinline__ void st_rel(u32* p, u32 v) {
  __hip_atomic_store(p, v, __ATOMIC_RELEASE, __HIP_MEMORY_SCOPE_WORKGROUP);
}
__device__ __forceinline__ u32 ld_acq(u32* p) {
  return __hip_atomic_load(p, __ATOMIC_ACQUIRE, __HIP_MEMORY_SCOPE_WORKGROUP);
}
__device__ __forceinline__ void spin_ge(u32* p, u32 v) {
  while (ld_acq(p) < v) {}
}

__device__ __forceinline__ u16 f2bf(float f) {
  unsigned u = __builtin_bit_cast(unsigned, f);
  u = (u + 0x7FFFu + ((u >> 16) & 1u)) >> 16;
  return (u16)u;
}
__device__ __forceinline__ float bf2f(u16 v) {
  unsigned u = ((unsigned)v) << 16;
  return __builtin_bit_cast(float, u);
}

// ---------------- prep: x fp32 -> bf16 ----------------
__global__ __launch_bounds__(256) void lstm_cvt_x(const float* __restrict__ x,
                                                  u16* __restrict__ xb) {
  int i = (blockIdx.x * 256 + threadIdx.x) * 4;
  float4 v = *reinterpret_cast<const float4*>(x + i);
  ushort4 o;
  o.x = f2bf(v.x); o.y = f2bf(v.y); o.z = f2bf(v.z); o.w = f2bf(v.w);
  *reinterpret_cast<ushort4*>(xb + i) = o;
}

// ---------------- prep: W [2048,4096] fp32 -> per-block LDS-image slices ----------------
// (verified R3-R10)  base idx: ((buf*2 + kh)*32 + ch)*512 + (slot*16 + brow)*8 + elem
__global__ __launch_bounds__(256) void lstm_prep_w(const float* __restrict__ W,
                                                   u16* __restrict__ wt_blk) {
  __shared__ float tile[32][33];
  int n0 = blockIdx.x * 32;
  int k0 = blockIdx.y * 32;
  int tc = threadIdx.x & 31;
  int tr = threadIdx.x >> 5;
#pragma unroll
  for (int i = 0; i < 4; ++i) {
    int k = tr + i * 8;
    tile[k][tc] = W[(size_t)(k0 + k) * NG + n0 + tc];
  }
  __syncthreads();
#pragma unroll
  for (int i = 0; i < 4; ++i) {
    int n = n0 + tr + i * 8;
    float wv = tile[tc][tr + i * 8];
    int k = k0 + tc;
    int g = n >> 10, col = n & 1023;
    int b = col >> 2, brow = g * 4 + (col & 3);
    int kh = k >> 10, ch = (k & 1023) >> 5;
    int slot = (k >> 3) & 3, elem = k & 7;
    size_t base = (size_t)b * 65536 + (size_t)(kh * 32 + ch) * 512
                + (size_t)(slot * 16 + brow) * 8 + elem;
    u16 hi = f2bf(wv);
    wt_blk[base] = hi;
    wt_blk[base + 32768] = f2bf(wv - bf2f(hi));
  }
}

// A-pass: 4 M-frags (rows i*16+arow), K=256 slice, hi+lo MFMA, 2-stage pipeline.
__device__ __forceinline__ void mfma_pass(const u16* __restrict__ a0, size_t rstride,
                                          const u16* __restrict__ Wl, int khalf,
                                          int kq, int lane, f32x4 acc[4]) {
  bf16x8 pf[4], qf[4];
#pragma unroll
  for (int i = 0; i < 4; ++i)
    pf[i] = *reinterpret_cast<const bf16x8*>(a0 + (size_t)i * 16 * rstride);
#pragma unroll
  for (int cc = 0; cc < 8; ++cc) {
    if (cc < 7) {
#pragma unroll
      for (int i = 0; i < 4; ++i)
        qf[i] = *reinterpret_cast<const bf16x8*>(a0 + (size_t)i * 16 * rstride + (cc + 1) * 32);
    }
    const int ch = kq * 8 + cc;
    const bf16x8 wh = *reinterpret_cast<const bf16x8*>(
        Wl + (size_t)(khalf * 32 + ch) * 512 + lane * 8);
    const bf16x8 wl2 = *reinterpret_cast<const bf16x8*>(
        Wl + (size_t)(64 + khalf * 32 + ch) * 512 + lane * 8);
#pragma unroll
    for (int i = 0; i < 4; ++i)
      acc[i] = __builtin_amdgcn_mfma_f32_16x16x32_bf16(pf[i], wh, acc[i], 0, 0, 0);
#pragma unroll
    for (int i = 0; i < 4; ++i)
      acc[i] = __builtin_amdgcn_mfma_f32_16x16x32_bf16(pf[i], wl2, acc[i], 0, 0, 0);
#pragma unroll
    for (int i = 0; i < 4; ++i) pf[i] = qf[i];
  }
}

// ---------------- persistent LSTM, low-traffic rendezvous ----------------
// Same structure as R10 (barrier-free LDS stamps, x-waves 1 step ahead).
// Rendezvous change: producers do ONE atomic add to cnt[t+1][b&7]; ONE wave
// per block (wave 6, lanes 0-7, s_sleep-paced) polls the 8 sub-counters and
// broadcasts via LDS stamp st[10]. Waves 4,5,7 spin only on LDS. Poll LLC
// traffic drops ~32x per sweep and pollers are paced -> stores/adds no longer
// queue behind poll storms.
__global__ __launch_bounds__(512) void lstm_persist(
    const u16* __restrict__ xb, u16* __restrict__ hseq,
    const u16* __restrict__ wt_blk, const float* __restrict__ bias,
    float* __restrict__ out, u32* __restrict__ cnt) {
  extern __shared__ char smem[];
  u16* Wl = (u16*)smem;
  float (*zsx)[2][64][17] = (float(*)[2][64][17])(smem + W_LDS_BYTES);
  float (*zsh)[64][17] = (float(*)[64][17])(smem + W_LDS_BYTES + ZSX_BYTES);
  u32* st = (u32*)(smem + W_LDS_BYTES + ZSX_BYTES + ZSH_BYTES);

  const int b = blockIdx.x;
  const int tid = threadIdx.x;
  const int lane = tid & 63;
  const int w = tid >> 6;
  const bool is_x = (w < 4);
  const int kq = w & 3;

  // ---- load W slice (128 KiB) into LDS ----
  {
    const u16* src = wt_blk + (size_t)b * 65536;
#pragma unroll
    for (int it = 0; it < 16; ++it) {
      uint4 v = *reinterpret_cast<const uint4*>(src + (size_t)it * 4096 + tid * 8);
      *reinterpret_cast<uint4*>(Wl + (size_t)it * 4096 + tid * 8) = v;
    }
  }
  // zero zsh (t=0 has no h contribution) and stamps
  for (int i = tid; i < 2 * 64 * 17; i += 512) ((float*)zsh)[i] = 0.f;
  if (tid < 16) st[tid] = 0u;

  const int arow = lane & 15;
  const int kfr = 8 * (lane >> 4);
  const int kbase = kq * 256 + kfr;
  const int zn = lane & 15;
  const int mg = (lane >> 4) * 4;

  // pointwise ownership (waves 4,5): idx = (w-4)*64 + lane -> (prow, 2 cols)
  const int hq = w - 4;
  const int idx = hq * 64 + lane;
  const int prow = idx >> 1;
  const int pc = (idx & 1) * 2;
  const int gc0 = b * 4 + pc;
  float bz[2][4];
  float creg[2] = {0.f, 0.f};
  if (w == 4 || w == 5) {
#pragma unroll
    for (int j = 0; j < 2; ++j) {
      bz[j][0] = bias[gc0 + j];
      bz[j][1] = bias[NH + gc0 + j];
      bz[j][2] = bias[2 * NH + gc0 + j];
      bz[j][3] = bias[3 * NH + gc0 + j];
    }
  }
  __syncthreads();  // prologue only

#pragma unroll 1
  for (int t = 0; t < NT; ++t) {
    if (is_x) {
      // ---- x-GEMM for step t into zsx[t&1]; gate: pointwise(t-2) done ----
      const u32 vreq = (t < 2) ? 0u : (u32)(t - 1);
      spin_ge(&st[8], vreq);
      spin_ge(&st[9], vreq);
      f32x4 acc[4] = {};
      const u16* a0 = xb + ((size_t)arow * NT + t) * NF + kbase;
      mfma_pass(a0, (size_t)NT * NF, Wl, 0, kq, lane, acc);
      const int buf = t & 1;
      if (w < 2) {
#pragma unroll
        for (int i = 0; i < 4; ++i)
#pragma unroll
          for (int r = 0; r < 4; ++r) zsx[buf][w][i * 16 + mg + r][zn] = acc[i][r];
        st_rel(&st[0 + w], (u32)(t + 1));
      } else {
        spin_ge(&st[0 + (w - 2)], (u32)(t + 1));
#pragma unroll
        for (int i = 0; i < 4; ++i)
#pragma unroll
          for (int r = 0; r < 4; ++r) zsx[buf][w - 2][i * 16 + mg + r][zn] += acc[i][r];
        st_rel(&st[2 + (w - 2)], (u32)(t + 1));
      }
    } else {
      // ---- h-GEMM for step t (K-quarter kq) ----
      f32x4 acc[4] = {};
      if (t > 0) {
        // ---- rendezvous: wave 6 polls 8 sub-counters, LDS-broadcasts ----
        if (hq == 2) {
          if (lane < 8) {
            const u32* cp = cnt + (size_t)t * 8 + lane;
            while (__hip_atomic_load(cp, __ATOMIC_RELAXED,
                                     __HIP_MEMORY_SCOPE_AGENT) < 32u)
              __builtin_amdgcn_s_sleep(1);
          }
          if (lane == 0) st_rel(&st[10], (u32)t);
        }
        spin_ge(&st[10], (u32)t);

        // bulk PLAIN load (rendezvous proves all h at LLC; fills are fresh)
        const u16* h0 = hseq + (size_t)t * NBH + (size_t)arow * NH + kbase;
        uint4 v[32];
#pragma unroll
        for (int cc = 0; cc < 8; ++cc)
#pragma unroll
          for (int i = 0; i < 4; ++i)
            v[cc * 4 + i] = *reinterpret_cast<const uint4*>(
                h0 + (size_t)i * 16 * NH + cc * 32);
        __builtin_amdgcn_s_setprio(1);
#pragma unroll
        for (int cc = 0; cc < 8; ++cc) {
          const int ch = kq * 8 + cc;
          const bf16x8 wh = *reinterpret_cast<const bf16x8*>(
              Wl + (size_t)(32 + ch) * 512 + lane * 8);             // kh=1 hi
          const bf16x8 wlo = *reinterpret_cast<const bf16x8*>(
              Wl + (size_t)(96 + ch) * 512 + lane * 8);             // kh=1 lo
#pragma unroll
          for (int i = 0; i < 4; ++i) {
            union HU { uint4 q; bf16x8 f; } u;
            u.q = v[cc * 4 + i];
            acc[i] = __builtin_amdgcn_mfma_f32_16x16x32_bf16(u.f, wh, acc[i], 0, 0, 0);
            acc[i] = __builtin_amdgcn_mfma_f32_16x16x32_bf16(u.f, wlo, acc[i], 0, 0, 0);
          }
        }
        __builtin_amdgcn_s_setprio(0);
      }

      // ---- zsh exchange via stamps ----
      if (hq < 2) {
        // writer: ensure the OTHER pointwise wave finished reading zsh (t-1)
        spin_ge(&st[8 + (1 - hq)], (u32)t);
        if (t > 0) {
#pragma unroll
          for (int i = 0; i < 4; ++i)
#pragma unroll
            for (int r = 0; r < 4; ++r) zsh[hq][i * 16 + mg + r][zn] = acc[i][r];
        }
        st_rel(&st[4 + hq], (u32)(t + 1));
      } else {
        spin_ge(&st[4 + (hq - 2)], (u32)(t + 1));
        if (t > 0) {
#pragma unroll
          for (int i = 0; i < 4; ++i)
#pragma unroll
            for (int r = 0; r < 4; ++r) zsh[hq - 2][i * 16 + mg + r][zn] += acc[i][r];
        }
        st_rel(&st[6 + (hq - 2)], (u32)(t + 1));
      }

      // ---- pointwise + publish (waves 4,5 only) ----
      if (hq < 2) {
        spin_ge(&st[6], (u32)(t + 1));
        spin_ge(&st[7], (u32)(t + 1));
        spin_ge(&st[2], (u32)(t + 1));
        spin_ge(&st[3], (u32)(t + 1));
        const int cb = t & 1;
        float hn[2];
#pragma unroll
        for (int jj = 0; jj < 2; ++jj) {
          const int col = pc + jj;
          const float zi = zsx[cb][0][prow][col]      + zsx[cb][1][prow][col]      + zsh[0][prow][col]      + zsh[1][prow][col]      + bz[jj][0];
          const float zj = zsx[cb][0][prow][4 + col]  + zsx[cb][1][prow][4 + col]  + zsh[0][prow][4 + col]  + zsh[1][prow][4 + col]  + bz[jj][1];
          const float zf = zsx[cb][0][prow][8 + col]  + zsx[cb][1][prow][8 + col]  + zsh[0][prow][8 + col]  + zsh[1][prow][8 + col]  + bz[jj][2];
          const float zo = zsx[cb][0][prow][12 + col] + zsx[cb][1][prow][12 + col] + zsh[0][prow][12 + col] + zsh[1][prow][12 + col] + bz[jj][3];
          const float si = 1.f / (1.f + __expf(-zi));
          const float tj = tanhf(zj);
          const float sf = 1.f / (1.f + __expf(-(zf + 1.0f)));  // FORGET_BIAS = 1
          const float so = 1.f / (1.f + __expf(-zo));
          const float cn = creg[jj] * sf + si * tj;
          hn[jj] = tanhf(cn) * so;
          creg[jj] = cn;
        }
        float2 ov = {hn[0], hn[1]};
        *reinterpret_cast<float2*>(out + ((size_t)prow * NT + t) * NH + gc0) = ov;
        if (t < NT - 1) {
          u32 hv = (u32)f2bf(hn[0]) | ((u32)f2bf(hn[1]) << 16);
          __hip_atomic_store(
              reinterpret_cast<u32*>(hseq + (size_t)(t + 1) * NBH + (size_t)prow * NH + gc0),
              hv, __ATOMIC_RELAXED, __HIP_MEMORY_SCOPE_AGENT);
        }
        asm volatile("s_waitcnt vmcnt(0)" ::: "memory");  // h at LLC
        st_rel(&st[8 + hq], (u32)(t + 1));
        if (hq == 0 && t < NT - 1) {
          spin_ge(&st[9], (u32)(t + 1));  // wave 5 drained too
          if (lane == 0)
            __hip_atomic_fetch_add(&cnt[(size_t)(t + 1) * 8 + (b & 7)], 1u,
                                   __ATOMIC_RELAXED, __HIP_MEMORY_SCOPE_AGENT);
        }
      }
      // waves 6,7 fall through and pre-poll step t+1 while 4,5 finish t
    }
  }
}

extern "C" void kernel_launch(void* const* d_in, const int* in_sizes, int n_in,
                              void* d_out, int out_size, void* d_ws, size_t ws_size,
                              hipStream_t stream) {
  const float* x = (const float*)d_in[0];
  const float* W = (const float*)d_in[1];
  const float* bias = (const float*)d_in[2];
  float* out = (float*)d_out;

  char* ws = (char*)d_ws;
  u16* xb = (u16*)(ws);                                  // 16 MiB
  u16* wt_blk = (u16*)(ws + 16777216);                   // 32 MiB
  u16* hseq = (u16*)(ws + 50331648);                     // 16 MiB
  u32* cnt = (u32*)(ws + 67108864);                      // 4 KiB

  hipMemsetAsync(cnt, 0, NT * 8 * sizeof(u32), stream);  // per-replay

  lstm_cvt_x<<<(NB * NT * NF) / (256 * 4), 256, 0, stream>>>(x, xb);
  lstm_prep_w<<<dim3(NG / 32, NK / 32), 256, 0, stream>>>(W, wt_blk);

  hipFuncSetAttribute((const void*)lstm_persist,
                      hipFuncAttributeMaxDynamicSharedMemorySize, SMEM_BYTES);

  void* args[] = {(void*)&xb, (void*)&hseq, (void*)&wt_blk, (void*)&bias,
                  (void*)&out, (void*)&cnt};
  hipLaunchCooperativeKernel((void*)lstm_persist, dim3(256), dim3(512), args,
                             SMEM_BYTES, stream);
}

// Round 13
// 1562.032 us; speedup vs baseline: 1.6642x; 1.6642x over previous
//
#include <hip/hip_runtime.h>
#include <hip/hip_bf16.h>

typedef unsigned short u16;
typedef unsigned int u32;
typedef unsigned long long u64;
typedef __bf16 bf16x8 __attribute__((ext_vector_type(8)));
typedef float f32x4 __attribute__((ext_vector_type(4)));

#define NB 64
#define NT 128
#define NF 1024
#define NH 1024
#define NK 2048   // F+H
#define NG 4096   // 4H
#define NBH (NB * NH)

// LDS: W slice 128 KiB + zsx[2 buf][2][64][17] + zsh[2][64][17] + handshake
#define W_LDS_BYTES 131072
#define ZSX_BYTES (2 * 2 * 64 * 17 * 4)   // 17408
#define ZSH_BYTES (2 * 64 * 17 * 4)       // 8704
#define SMEM_BYTES (W_LDS_BYTES + ZSX_BYTES + ZSH_BYTES + 64)  // 157248 <= 163840

__device__ __forceinline__ u16 f2bf(float f) {
  unsigned u = __builtin_bit_cast(unsigned, f);
  u = (u + 0x7FFFu + ((u >> 16) & 1u)) >> 16;
  return (u16)u;
}
__device__ __forceinline__ float bf2f(u16 v) {
  unsigned u = ((unsigned)v) << 16;
  return __builtin_bit_cast(float, u);
}

// ---------------- prep: x fp32 -> bf16 ----------------
__global__ __launch_bounds__(256) void lstm_cvt_x(const float* __restrict__ x,
                                                  u16* __restrict__ xb) {
  int i = (blockIdx.x * 256 + threadIdx.x) * 4;
  float4 v = *reinterpret_cast<const float4*>(x + i);
  ushort4 o;
  o.x = f2bf(v.x); o.y = f2bf(v.y); o.z = f2bf(v.z); o.w = f2bf(v.w);
  *reinterpret_cast<ushort4*>(xb + i) = o;
}

// ---------------- prep: W [2048,4096] fp32 -> per-block LDS-image slices ----------------
// (verified R3-R11)  base idx: ((buf*2 + kh)*32 + ch)*512 + (slot*16 + brow)*8 + elem
__global__ __launch_bounds__(256) void lstm_prep_w(const float* __restrict__ W,
                                                   u16* __restrict__ wt_blk) {
  __shared__ float tile[32][33];
  int n0 = blockIdx.x * 32;
  int k0 = blockIdx.y * 32;
  int tc = threadIdx.x & 31;
  int tr = threadIdx.x >> 5;
#pragma unroll
  for (int i = 0; i < 4; ++i) {
    int k = tr + i * 8;
    tile[k][tc] = W[(size_t)(k0 + k) * NG + n0 + tc];
  }
  __syncthreads();
#pragma unroll
  for (int i = 0; i < 4; ++i) {
    int n = n0 + tr + i * 8;
    float wv = tile[tc][tr + i * 8];
    int k = k0 + tc;
    int g = n >> 10, col = n & 1023;
    int b = col >> 2, brow = g * 4 + (col & 3);
    int kh = k >> 10, ch = (k & 1023) >> 5;
    int slot = (k >> 3) & 3, elem = k & 7;
    size_t base = (size_t)b * 65536 + (size_t)(kh * 32 + ch) * 512
                + (size_t)(slot * 16 + brow) * 8 + elem;
    u16 hi = f2bf(wv);
    wt_blk[base] = hi;
    wt_blk[base + 32768] = f2bf(wv - bf2f(hi));
  }
}

// A-pass: 4 M-frags (rows i*16+arow), K=256 slice, hi+lo MFMA, 2-stage pipeline.
__device__ __forceinline__ void mfma_pass(const u16* __restrict__ a0, size_t rstride,
                                          const u16* __restrict__ Wl, int khalf,
                                          int kq, int lane, f32x4 acc[4]) {
  bf16x8 pf[4], qf[4];
#pragma unroll
  for (int i = 0; i < 4; ++i)
    pf[i] = *reinterpret_cast<const bf16x8*>(a0 + (size_t)i * 16 * rstride);
#pragma unroll
  for (int cc = 0; cc < 8; ++cc) {
    if (cc < 7) {
#pragma unroll
      for (int i = 0; i < 4; ++i)
        qf[i] = *reinterpret_cast<const bf16x8*>(a0 + (size_t)i * 16 * rstride + (cc + 1) * 32);
    }
    const int ch = kq * 8 + cc;
    const bf16x8 wh = *reinterpret_cast<const bf16x8*>(
        Wl + (size_t)(khalf * 32 + ch) * 512 + lane * 8);
    const bf16x8 wl2 = *reinterpret_cast<const bf16x8*>(
        Wl + (size_t)(64 + khalf * 32 + ch) * 512 + lane * 8);
#pragma unroll
    for (int i = 0; i < 4; ++i)
      acc[i] = __builtin_amdgcn_mfma_f32_16x16x32_bf16(pf[i], wh, acc[i], 0, 0, 0);
#pragma unroll
    for (int i = 0; i < 4; ++i)
      acc[i] = __builtin_amdgcn_mfma_f32_16x16x32_bf16(pf[i], wl2, acc[i], 0, 0, 0);
#pragma unroll
    for (int i = 0; i < 4; ++i) pf[i] = qf[i];
  }
}

// ---------------- persistent LSTM (R5 structure + staged output) ----------------
// 256 blocks x 512 threads. Waves 0-3: x-GEMM for step t+1 (zsx double buffer,
// one step ahead). Waves 4-7: h-GEMM for step t (poll 64 producer flags/wave).
// KEY CHANGE vs R5: the per-step fp32 output is NOT written to `out` (whose
// 16B-per-64B-line pattern caused write-allocate HBM RMWs inside the vmcnt(0)
// drain on the critical path every step). It goes to a column-major staging
// zo[t][col][row] (full-line coalesced agent stores, issued AFTER the flag
// publish). A final in-kernel phase (after a grid-wide done rendezvous)
// transposes zo -> out with coalesced full-line writes.
__global__ __launch_bounds__(512) void lstm_persist(
    const u16* __restrict__ xb, u16* __restrict__ hseq,
    const u16* __restrict__ wt_blk, const float* __restrict__ bias,
    float* __restrict__ out, u32* __restrict__ flags,
    float* __restrict__ zo) {
  extern __shared__ char smem[];
  u16* Wl = (u16*)smem;
  float (*zsx)[2][64][17] = (float(*)[2][64][17])(smem + W_LDS_BYTES);
  float (*zsh)[64][17] = (float(*)[64][17])(smem + W_LDS_BYTES + ZSX_BYTES);
  volatile u32* hsflag = (volatile u32*)(smem + W_LDS_BYTES + ZSX_BYTES + ZSH_BYTES);

  const int b = blockIdx.x;
  const int tid = threadIdx.x;
  const int lane = tid & 63;
  const int w = tid >> 6;
  const bool is_x = (w < 4);
  const int kq = w & 3;

  // ---- load W slice (128 KiB) into LDS ----
  {
    const u16* src = wt_blk + (size_t)b * 65536;
#pragma unroll
    for (int it = 0; it < 16; ++it) {
      uint4 v = *reinterpret_cast<const uint4*>(src + (size_t)it * 4096 + tid * 8);
      *reinterpret_cast<uint4*>(Wl + (size_t)it * 4096 + tid * 8) = v;
    }
  }
  // zero zsh (t=0 has no h contribution)
  for (int i = tid; i < 2 * 64 * 17; i += 512) ((float*)zsh)[i] = 0.f;
  if (tid == 0) hsflag[0] = 0u;

  const int arow = lane & 15;
  const int kfr = 8 * (lane >> 4);
  const int kbase = kq * 256 + kfr;
  const int zn = lane & 15;
  const int mg = (lane >> 4) * 4;

  // pointwise ownership: tid<128 owns (prow, 2 cols)
  const int prow = tid >> 1;
  const int pc = (tid & 1) * 2;
  const int gc0 = b * 4 + pc;
  float bz[2][4];
  float creg[2] = {0.f, 0.f};
  if (tid < 128) {
#pragma unroll
    for (int j = 0; j < 2; ++j) {
      bz[j][0] = bias[gc0 + j];
      bz[j][1] = bias[NH + gc0 + j];
      bz[j][2] = bias[2 * NH + gc0 + j];
      bz[j][3] = bias[3 * NH + gc0 + j];
    }
  }
  __syncthreads();

  // ---- prologue: x-waves fill zsx[0] = zx(0) ----
  {
    f32x4 acc[4] = {};
    if (is_x) {
      const u16* a0 = xb + ((size_t)arow * NT + 0) * NF + kbase;
      mfma_pass(a0, (size_t)NT * NF, Wl, 0, kq, lane, acc);
      if (w < 2) {
#pragma unroll
        for (int i = 0; i < 4; ++i)
#pragma unroll
          for (int r = 0; r < 4; ++r) zsx[0][w][i * 16 + mg + r][zn] = acc[i][r];
      }
    }
    __syncthreads();
    if (is_x && w >= 2) {
#pragma unroll
      for (int i = 0; i < 4; ++i)
#pragma unroll
        for (int r = 0; r < 4; ++r) zsx[0][w - 2][i * 16 + mg + r][zn] += acc[i][r];
    }
    __syncthreads();
  }

#pragma unroll 1
  for (int t = 0; t < NT; ++t) {
    const int cb = t & 1;        // zsx buffer consumed this step
    const int nb = (t + 1) & 1;  // zsx buffer filled this step
    f32x4 acc[4] = {};

    if (is_x) {
      if (t < NT - 1) {
        const u16* a0 = xb + ((size_t)arow * NT + (t + 1)) * NF + kbase;
        mfma_pass(a0, (size_t)NT * NF, Wl, 0, kq, lane, acc);
      }
    } else {
      if (t > 0) {
        // dataflow poll: wave kq's h-cols come from blocks [64kq, 64kq+64)
        const u32* fp = flags + (size_t)t * 256 + kq * 64 + lane;
        u32 v;
        do {
          v = __hip_atomic_load(fp, __ATOMIC_RELAXED, __HIP_MEMORY_SCOPE_AGENT);
        } while (!__all(v != 0));
        const u16* a0 = hseq + (size_t)t * NBH + (size_t)arow * NH + kbase;
        __builtin_amdgcn_s_setprio(1);
        mfma_pass(a0, (size_t)NH, Wl, 1, kq, lane, acc);
        __builtin_amdgcn_s_setprio(0);
      }
    }

    // ---- write phase ----
    if (is_x) {
      if (w < 2 && t < NT - 1) {
#pragma unroll
        for (int i = 0; i < 4; ++i)
#pragma unroll
          for (int r = 0; r < 4; ++r) zsx[nb][w][i * 16 + mg + r][zn] = acc[i][r];
      }
    } else {
      if (w < 6 && t > 0) {
#pragma unroll
        for (int i = 0; i < 4; ++i)
#pragma unroll
          for (int r = 0; r < 4; ++r) zsh[w - 4][i * 16 + mg + r][zn] = acc[i][r];
      }
    }
    __syncthreads();
    // ---- add phase ----
    if (is_x) {
      if (w >= 2 && t < NT - 1) {
#pragma unroll
        for (int i = 0; i < 4; ++i)
#pragma unroll
          for (int r = 0; r < 4; ++r) zsx[nb][w - 2][i * 16 + mg + r][zn] += acc[i][r];
      }
    } else {
      if (w >= 6 && t > 0) {
#pragma unroll
        for (int i = 0; i < 4; ++i)
#pragma unroll
          for (int r = 0; r < 4; ++r) zsh[w - 6][i * 16 + mg + r][zn] += acc[i][r];
      }
    }
    __syncthreads();

    // ---- fused pointwise + h publish + staged output ----
    if (tid < 128) {
      float hn[2];
#pragma unroll
      for (int jj = 0; jj < 2; ++jj) {
        const int col = pc + jj;
        const float zi = zsx[cb][0][prow][col]      + zsx[cb][1][prow][col]      + zsh[0][prow][col]      + zsh[1][prow][col]      + bz[jj][0];
        const float zj = zsx[cb][0][prow][4 + col]  + zsx[cb][1][prow][4 + col]  + zsh[0][prow][4 + col]  + zsh[1][prow][4 + col]  + bz[jj][1];
        const float zf = zsx[cb][0][prow][8 + col]  + zsx[cb][1][prow][8 + col]  + zsh[0][prow][8 + col]  + zsh[1][prow][8 + col]  + bz[jj][2];
        const float zo4 = zsx[cb][0][prow][12 + col] + zsx[cb][1][prow][12 + col] + zsh[0][prow][12 + col] + zsh[1][prow][12 + col] + bz[jj][3];
        const float si = 1.f / (1.f + __expf(-zi));
        const float tj = tanhf(zj);
        const float sf = 1.f / (1.f + __expf(-(zf + 1.0f)));  // FORGET_BIAS = 1
        const float so = 1.f / (1.f + __expf(-zo4));
        const float cn = creg[jj] * sf + si * tj;
        hn[jj] = tanhf(cn) * so;
        creg[jj] = cn;
      }
      if (t < NT - 1) {
        // h publish (agent store -> LLC), drain ONLY these before the flag
        u32 hv = (u32)f2bf(hn[0]) | ((u32)f2bf(hn[1]) << 16);
        __hip_atomic_store(
            reinterpret_cast<u32*>(hseq + (size_t)(t + 1) * NBH + (size_t)prow * NH + gc0),
            hv, __ATOMIC_RELAXED, __HIP_MEMORY_SCOPE_AGENT);
        asm volatile("s_waitcnt vmcnt(0)" ::: "memory");  // h at LLC (no out RMW here!)
        if (tid == 64) hsflag[0] = (u32)(t + 1);          // wave 1 drained
        if (tid == 0) {
          while (hsflag[0] != (u32)(t + 1)) {}            // wait wave 1
          __hip_atomic_store(&flags[(size_t)(t + 1) * 256 + b], 1u,
                             __ATOMIC_RELAXED, __HIP_MEMORY_SCOPE_AGENT);
        }
      }
      // staged output: column-major zo[t][col][row] -> full-line coalesced,
      // issued AFTER the flag publish (completely off the critical path)
#pragma unroll
      for (int jj = 0; jj < 2; ++jj) {
        __hip_atomic_store(
            reinterpret_cast<u32*>(zo + ((size_t)t * NH + gc0 + jj) * NB + prow),
            __builtin_bit_cast(u32, hn[jj]),
            __ATOMIC_RELAXED, __HIP_MEMORY_SCOPE_AGENT);
      }
    }
    // h-waves proceed to poll step t+1 while waves 0-1 finish the tail
  }

  // ================= final: grid rendezvous, then zo -> out transpose =========
  __syncthreads();
  asm volatile("s_waitcnt vmcnt(0)" ::: "memory");  // all zo stores at LLC
  if (tid == 0)
    __hip_atomic_store(&flags[b], 1u, __ATOMIC_RELAXED,
                       __HIP_MEMORY_SCOPE_AGENT);  // reuse flags row t=0
  if (w == 0) {
    const u32* dp = flags + lane * 4;
    bool ok;
    do {
      u32 v0 = __hip_atomic_load(dp + 0, __ATOMIC_RELAXED, __HIP_MEMORY_SCOPE_AGENT);
      u32 v1 = __hip_atomic_load(dp + 1, __ATOMIC_RELAXED, __HIP_MEMORY_SCOPE_AGENT);
      u32 v2 = __hip_atomic_load(dp + 2, __ATOMIC_RELAXED, __HIP_MEMORY_SCOPE_AGENT);
      u32 v3 = __hip_atomic_load(dp + 3, __ATOMIC_RELAXED, __HIP_MEMORY_SCOPE_AGENT);
      ok = ((v0 & v1 & v2 & v3) == 1u);
    } while (!__all(ok));
  }
  __syncthreads();

  // block b: slab ts = b>>1, rows [r0, r0+32). LDS tile reuses the W region.
  {
    const int ts = b >> 1;
    const int r0 = (b & 1) * 32;
    float* T = (float*)smem;  // [32][1028] floats = 131584 B < SMEM_BYTES
#pragma unroll 4
    for (int it = 0; it < 16; ++it) {
      int flat = it * 512 + tid;   // 8192 float4 chunks
      int c = flat >> 3;           // col 0..1023
      int q = flat & 7;            // row quad
      const u64* p = reinterpret_cast<const u64*>(
          zo + ((size_t)ts * NH + c) * NB + r0 + q * 4);
      u64 lo = __hip_atomic_load(p + 0, __ATOMIC_RELAXED, __HIP_MEMORY_SCOPE_AGENT);
      u64 hi = __hip_atomic_load(p + 1, __ATOMIC_RELAXED, __HIP_MEMORY_SCOPE_AGENT);
      T[(q * 4 + 0) * 1028 + c] = __builtin_bit_cast(float, (u32)lo);
      T[(q * 4 + 1) * 1028 + c] = __builtin_bit_cast(float, (u32)(lo >> 32));
      T[(q * 4 + 2) * 1028 + c] = __builtin_bit_cast(float, (u32)hi);
      T[(q * 4 + 3) * 1028 + c] = __builtin_bit_cast(float, (u32)(hi >> 32));
    }
    __syncthreads();
#pragma unroll 4
    for (int it = 0; it < 16; ++it) {
      int flat = it * 512 + tid;   // 8192 float4 writes
      int r = flat >> 8;           // 0..31
      int c4 = flat & 255;         // float4 col group
      float4 v;
      v.x = T[r * 1028 + c4 * 4 + 0];
      v.y = T[r * 1028 + c4 * 4 + 1];
      v.z = T[r * 1028 + c4 * 4 + 2];
      v.w = T[r * 1028 + c4 * 4 + 3];
      *reinterpret_cast<float4*>(
          out + ((size_t)(r0 + r) * NT + ts) * NH + c4 * 4) = v;
    }
  }
}

extern "C" void kernel_launch(void* const* d_in, const int* in_sizes, int n_in,
                              void* d_out, int out_size, void* d_ws, size_t ws_size,
                              hipStream_t stream) {
  const float* x = (const float*)d_in[0];
  const float* W = (const float*)d_in[1];
  const float* bias = (const float*)d_in[2];
  float* out = (float*)d_out;

  char* ws = (char*)d_ws;
  u16* xb = (u16*)(ws);                                  // 16 MiB
  u16* wt_blk = (u16*)(ws + 16777216);                   // 32 MiB
  u16* hseq = (u16*)(ws + 50331648);                     // 16 MiB
  u32* flags = (u32*)(ws + 67108864);                    // 128 KiB
  float* zo = (float*)(ws + 67239936);                   // 32 MiB (staging, col-major)

  hipMemsetAsync(hseq, 0, NBH * sizeof(u16), stream);        // h_0 = 0
  hipMemsetAsync(flags, 0, NT * 256 * sizeof(u32), stream);  // per-replay

  lstm_cvt_x<<<(NB * NT * NF) / (256 * 4), 256, 0, stream>>>(x, xb);
  lstm_prep_w<<<dim3(NG / 32, NK / 32), 256, 0, stream>>>(W, wt_blk);

  hipFuncSetAttribute((const void*)lstm_persist,
                      hipFuncAttributeMaxDynamicSharedMemorySize, SMEM_BYTES);

  void* args[] = {(void*)&xb, (void*)&hseq, (void*)&wt_blk, (void*)&bias,
                  (void*)&out, (void*)&flags, (void*)&zo};
  hipLaunchCooperativeKernel((void*)lstm_persist, dim3(256), dim3(512), args,
                             SMEM_BYTES, stream);
}

// Round 14
// 1206.760 us; speedup vs baseline: 2.1542x; 1.2944x over previous
//
#include <hip/hip_runtime.h>
#include <hip/hip_bf16.h>

typedef unsigned short u16;
typedef unsigned int u32;
typedef unsigned long long u64;
typedef __bf16 bf16x8 __attribute__((ext_vector_type(8)));
typedef float f32x4 __attribute__((ext_vector_type(4)));

#define NB 64
#define NT 128
#define NF 1024
#define NH 1024
#define NK 2048   // F+H
#define NG 4096   // 4H
#define NBH (NB * NH)

// LDS: W slice 128 KiB + zsx[2 buf][2][64][17] + zsh[2][64][17] + handshake
#define W_LDS_BYTES 131072
#define ZSX_BYTES (2 * 2 * 64 * 17 * 4)   // 17408
#define ZSH_BYTES (2 * 64 * 17 * 4)       // 8704
#define SMEM_BYTES (W_LDS_BYTES + ZSX_BYTES + ZSH_BYTES + 64)  // 157248 <= 163840

__device__ __forceinline__ u16 f2bf(float f) {
  unsigned u = __builtin_bit_cast(unsigned, f);
  u = (u + 0x7FFFu + ((u >> 16) & 1u)) >> 16;
  return (u16)u;
}
__device__ __forceinline__ float bf2f(u16 v) {
  unsigned u = ((unsigned)v) << 16;
  return __builtin_bit_cast(float, u);
}

// ---------------- prep: x fp32 -> bf16 ----------------
__global__ __launch_bounds__(256) void lstm_cvt_x(const float* __restrict__ x,
                                                  u16* __restrict__ xb) {
  int i = (blockIdx.x * 256 + threadIdx.x) * 4;
  float4 v = *reinterpret_cast<const float4*>(x + i);
  ushort4 o;
  o.x = f2bf(v.x); o.y = f2bf(v.y); o.z = f2bf(v.z); o.w = f2bf(v.w);
  *reinterpret_cast<ushort4*>(xb + i) = o;
}

// ---------------- prep: W [2048,4096] fp32 -> per-block LDS-image slices ----------------
// (verified R3-R13)  base idx: ((buf*2 + kh)*32 + ch)*512 + (slot*16 + brow)*8 + elem
__global__ __launch_bounds__(256) void lstm_prep_w(const float* __restrict__ W,
                                                   u16* __restrict__ wt_blk) {
  __shared__ float tile[32][33];
  int n0 = blockIdx.x * 32;
  int k0 = blockIdx.y * 32;
  int tc = threadIdx.x & 31;
  int tr = threadIdx.x >> 5;
#pragma unroll
  for (int i = 0; i < 4; ++i) {
    int k = tr + i * 8;
    tile[k][tc] = W[(size_t)(k0 + k) * NG + n0 + tc];
  }
  __syncthreads();
#pragma unroll
  for (int i = 0; i < 4; ++i) {
    int n = n0 + tr + i * 8;
    float wv = tile[tc][tr + i * 8];
    int k = k0 + tc;
    int g = n >> 10, col = n & 1023;
    int b = col >> 2, brow = g * 4 + (col & 3);
    int kh = k >> 10, ch = (k & 1023) >> 5;
    int slot = (k >> 3) & 3, elem = k & 7;
    size_t base = (size_t)b * 65536 + (size_t)(kh * 32 + ch) * 512
                + (size_t)(slot * 16 + brow) * 8 + elem;
    u16 hi = f2bf(wv);
    wt_blk[base] = hi;
    wt_blk[base + 32768] = f2bf(wv - bf2f(hi));
  }
}

// x A-pass: 4 M-frags (rows i*16+arow), K=256 slice, hi+lo MFMA, 2-stage pipeline.
__device__ __forceinline__ void mfma_pass(const u16* __restrict__ a0, size_t rstride,
                                          const u16* __restrict__ Wl, int khalf,
                                          int kq, int lane, f32x4 acc[4]) {
  bf16x8 pf[4], qf[4];
#pragma unroll
  for (int i = 0; i < 4; ++i)
    pf[i] = *reinterpret_cast<const bf16x8*>(a0 + (size_t)i * 16 * rstride);
#pragma unroll
  for (int cc = 0; cc < 8; ++cc) {
    if (cc < 7) {
#pragma unroll
      for (int i = 0; i < 4; ++i)
        qf[i] = *reinterpret_cast<const bf16x8*>(a0 + (size_t)i * 16 * rstride + (cc + 1) * 32);
    }
    const int ch = kq * 8 + cc;
    const bf16x8 wh = *reinterpret_cast<const bf16x8*>(
        Wl + (size_t)(khalf * 32 + ch) * 512 + lane * 8);
    const bf16x8 wl2 = *reinterpret_cast<const bf16x8*>(
        Wl + (size_t)(64 + khalf * 32 + ch) * 512 + lane * 8);
#pragma unroll
    for (int i = 0; i < 4; ++i)
      acc[i] = __builtin_amdgcn_mfma_f32_16x16x32_bf16(pf[i], wh, acc[i], 0, 0, 0);
#pragma unroll
    for (int i = 0; i < 4; ++i)
      acc[i] = __builtin_amdgcn_mfma_f32_16x16x32_bf16(pf[i], wl2, acc[i], 0, 0, 0);
#pragma unroll
    for (int i = 0; i < 4; ++i) pf[i] = qf[i];
  }
}

// ---------------- persistent LSTM (R13 structure + SLAB-COALESCED h exchange) ----
// hseq layout: [t][producer block pb][row 0..64][4 cols] -- 512 B contiguous
// per block. Producer: 128 consecutive u32 agent stores (8 LLC lines vs 128
// scattered in R5-R13 -> 16x fewer LLC write transactions; vmcnt(0) drain acks
// 8 lines). Consumer: lane's bf16x8 = two u64 from adjacent slabs; lanes 0-15
// read consecutive u64s (128 B segments), L2-cached after first fill per XCD.
__global__ __launch_bounds__(512) void lstm_persist(
    const u16* __restrict__ xb, u16* __restrict__ hseq,
    const u16* __restrict__ wt_blk, const float* __restrict__ bias,
    float* __restrict__ out, u32* __restrict__ flags,
    float* __restrict__ zo) {
  extern __shared__ char smem[];
  u16* Wl = (u16*)smem;
  float (*zsx)[2][64][17] = (float(*)[2][64][17])(smem + W_LDS_BYTES);
  float (*zsh)[64][17] = (float(*)[64][17])(smem + W_LDS_BYTES + ZSX_BYTES);
  volatile u32* hsflag = (volatile u32*)(smem + W_LDS_BYTES + ZSX_BYTES + ZSH_BYTES);

  const int b = blockIdx.x;
  const int tid = threadIdx.x;
  const int lane = tid & 63;
  const int w = tid >> 6;
  const bool is_x = (w < 4);
  const int kq = w & 3;

  // ---- load W slice (128 KiB) into LDS ----
  {
    const u16* src = wt_blk + (size_t)b * 65536;
#pragma unroll
    for (int it = 0; it < 16; ++it) {
      uint4 v = *reinterpret_cast<const uint4*>(src + (size_t)it * 4096 + tid * 8);
      *reinterpret_cast<uint4*>(Wl + (size_t)it * 4096 + tid * 8) = v;
    }
  }
  // zero zsh (t=0 has no h contribution)
  for (int i = tid; i < 2 * 64 * 17; i += 512) ((float*)zsh)[i] = 0.f;
  if (tid == 0) hsflag[0] = 0u;

  const int arow = lane & 15;
  const int kfr = 8 * (lane >> 4);
  const int kbase = kq * 256 + kfr;
  const int zn = lane & 15;
  const int mg = (lane >> 4) * 4;

  // pointwise ownership: tid<128 owns (prow, 2 cols)
  const int prow = tid >> 1;
  const int pc = (tid & 1) * 2;
  const int gc0 = b * 4 + pc;
  float bz[2][4];
  float creg[2] = {0.f, 0.f};
  if (tid < 128) {
#pragma unroll
    for (int j = 0; j < 2; ++j) {
      bz[j][0] = bias[gc0 + j];
      bz[j][1] = bias[NH + gc0 + j];
      bz[j][2] = bias[2 * NH + gc0 + j];
      bz[j][3] = bias[3 * NH + gc0 + j];
    }
  }
  __syncthreads();

  // ---- prologue: x-waves fill zsx[0] = zx(0) ----
  {
    f32x4 acc[4] = {};
    if (is_x) {
      const u16* a0 = xb + ((size_t)arow * NT + 0) * NF + kbase;
      mfma_pass(a0, (size_t)NT * NF, Wl, 0, kq, lane, acc);
      if (w < 2) {
#pragma unroll
        for (int i = 0; i < 4; ++i)
#pragma unroll
          for (int r = 0; r < 4; ++r) zsx[0][w][i * 16 + mg + r][zn] = acc[i][r];
      }
    }
    __syncthreads();
    if (is_x && w >= 2) {
#pragma unroll
      for (int i = 0; i < 4; ++i)
#pragma unroll
        for (int r = 0; r < 4; ++r) zsx[0][w - 2][i * 16 + mg + r][zn] += acc[i][r];
    }
    __syncthreads();
  }

#pragma unroll 1
  for (int t = 0; t < NT; ++t) {
    const int cb = t & 1;        // zsx buffer consumed this step
    const int nb = (t + 1) & 1;  // zsx buffer filled this step
    f32x4 acc[4] = {};

    if (is_x) {
      if (t < NT - 1) {
        const u16* a0 = xb + ((size_t)arow * NT + (t + 1)) * NF + kbase;
        mfma_pass(a0, (size_t)NT * NF, Wl, 0, kq, lane, acc);
      }
    } else {
      if (t > 0) {
        // dataflow poll: wave kq's h-cols come from blocks [64kq, 64kq+64)
        const u32* fp = flags + (size_t)t * 256 + kq * 64 + lane;
        u32 v;
        do {
          v = __hip_atomic_load(fp, __ATOMIC_RELAXED, __HIP_MEMORY_SCOPE_AGENT);
        } while (!__all(v != 0));

        // ---- slab-layout h-GEMM: lane's bf16x8 = u64 pair from slabs ----
        // slab s covers cols [4s, 4s+4); chunk cc: c = kq*256 + cc*32 + kfr
        // -> s0 = kq*64 + cc*8 + 2*(lane>>4)
        const u64* hb = reinterpret_cast<const u64*>(hseq) + (size_t)t * (256 * 64);
        const int sbase = kq * 64 + 2 * (lane >> 4);
        u64 plo[4], phi[4], qlo[4], qhi[4];
#pragma unroll
        for (int i = 0; i < 4; ++i) {
          plo[i] = hb[(size_t)sbase * 64 + arow + 16 * i];
          phi[i] = hb[(size_t)(sbase + 1) * 64 + arow + 16 * i];
        }
        __builtin_amdgcn_s_setprio(1);
#pragma unroll
        for (int cc = 0; cc < 8; ++cc) {
          if (cc < 7) {
            const int s = sbase + (cc + 1) * 8;
#pragma unroll
            for (int i = 0; i < 4; ++i) {
              qlo[i] = hb[(size_t)s * 64 + arow + 16 * i];
              qhi[i] = hb[(size_t)(s + 1) * 64 + arow + 16 * i];
            }
          }
          const int ch = kq * 8 + cc;
          const bf16x8 wh = *reinterpret_cast<const bf16x8*>(
              Wl + (size_t)(32 + ch) * 512 + lane * 8);             // kh=1 hi
          const bf16x8 wlo = *reinterpret_cast<const bf16x8*>(
              Wl + (size_t)(96 + ch) * 512 + lane * 8);             // kh=1 lo
#pragma unroll
          for (int i = 0; i < 4; ++i) {
            union HU { u64 q[2]; bf16x8 f; } u;
            u.q[0] = plo[i];
            u.q[1] = phi[i];
            acc[i] = __builtin_amdgcn_mfma_f32_16x16x32_bf16(u.f, wh, acc[i], 0, 0, 0);
            acc[i] = __builtin_amdgcn_mfma_f32_16x16x32_bf16(u.f, wlo, acc[i], 0, 0, 0);
          }
#pragma unroll
          for (int i = 0; i < 4; ++i) { plo[i] = qlo[i]; phi[i] = qhi[i]; }
        }
        __builtin_amdgcn_s_setprio(0);
      }
    }

    // ---- write phase ----
    if (is_x) {
      if (w < 2 && t < NT - 1) {
#pragma unroll
        for (int i = 0; i < 4; ++i)
#pragma unroll
          for (int r = 0; r < 4; ++r) zsx[nb][w][i * 16 + mg + r][zn] = acc[i][r];
      }
    } else {
      if (w < 6 && t > 0) {
#pragma unroll
        for (int i = 0; i < 4; ++i)
#pragma unroll
          for (int r = 0; r < 4; ++r) zsh[w - 4][i * 16 + mg + r][zn] = acc[i][r];
      }
    }
    __syncthreads();
    // ---- add phase ----
    if (is_x) {
      if (w >= 2 && t < NT - 1) {
#pragma unroll
        for (int i = 0; i < 4; ++i)
#pragma unroll
          for (int r = 0; r < 4; ++r) zsx[nb][w - 2][i * 16 + mg + r][zn] += acc[i][r];
      }
    } else {
      if (w >= 6 && t > 0) {
#pragma unroll
        for (int i = 0; i < 4; ++i)
#pragma unroll
          for (int r = 0; r < 4; ++r) zsh[w - 6][i * 16 + mg + r][zn] += acc[i][r];
      }
    }
    __syncthreads();

    // ---- fused pointwise + coalesced h publish + staged output ----
    if (tid < 128) {
      float hn[2];
#pragma unroll
      for (int jj = 0; jj < 2; ++jj) {
        const int col = pc + jj;
        const float zi = zsx[cb][0][prow][col]      + zsx[cb][1][prow][col]      + zsh[0][prow][col]      + zsh[1][prow][col]      + bz[jj][0];
        const float zj = zsx[cb][0][prow][4 + col]  + zsx[cb][1][prow][4 + col]  + zsh[0][prow][4 + col]  + zsh[1][prow][4 + col]  + bz[jj][1];
        const float zf = zsx[cb][0][prow][8 + col]  + zsx[cb][1][prow][8 + col]  + zsh[0][prow][8 + col]  + zsh[1][prow][8 + col]  + bz[jj][2];
        const float zo4 = zsx[cb][0][prow][12 + col] + zsx[cb][1][prow][12 + col] + zsh[0][prow][12 + col] + zsh[1][prow][12 + col] + bz[jj][3];
        const float si = 1.f / (1.f + __expf(-zi));
        const float tj = tanhf(zj);
        const float sf = 1.f / (1.f + __expf(-(zf + 1.0f)));  // FORGET_BIAS = 1
        const float so = 1.f / (1.f + __expf(-zo4));
        const float cn = creg[jj] * sf + si * tj;
        hn[jj] = tanhf(cn) * so;
        creg[jj] = cn;
      }
      if (t < NT - 1) {
        // h publish: SLAB layout -> 128 consecutive u32 = 512 B, 8 LLC lines
        u32 hv = (u32)f2bf(hn[0]) | ((u32)f2bf(hn[1]) << 16);
        u32* hp = reinterpret_cast<u32*>(hseq)
                + ((size_t)(t + 1) * 256 + b) * 128 + prow * 2 + (pc >> 1);
        __hip_atomic_store(hp, hv, __ATOMIC_RELAXED, __HIP_MEMORY_SCOPE_AGENT);
        asm volatile("s_waitcnt vmcnt(0)" ::: "memory");  // 8-line ack
        if (tid == 64) hsflag[0] = (u32)(t + 1);          // wave 1 drained
        if (tid == 0) {
          while (hsflag[0] != (u32)(t + 1)) {}            // wait wave 1
          __hip_atomic_store(&flags[(size_t)(t + 1) * 256 + b], 1u,
                             __ATOMIC_RELAXED, __HIP_MEMORY_SCOPE_AGENT);
        }
      }
      // staged output: column-major zo[t][col][row], after the flag publish
#pragma unroll
      for (int jj = 0; jj < 2; ++jj) {
        __hip_atomic_store(
            reinterpret_cast<u32*>(zo + ((size_t)t * NH + gc0 + jj) * NB + prow),
            __builtin_bit_cast(u32, hn[jj]),
            __ATOMIC_RELAXED, __HIP_MEMORY_SCOPE_AGENT);
      }
    }
    // h-waves proceed to poll step t+1 while waves 0-1 finish the tail
  }

  // ================= final: grid rendezvous, then zo -> out transpose =========
  __syncthreads();
  asm volatile("s_waitcnt vmcnt(0)" ::: "memory");  // all zo stores at LLC
  if (tid == 0)
    __hip_atomic_store(&flags[b], 1u, __ATOMIC_RELAXED,
                       __HIP_MEMORY_SCOPE_AGENT);  // reuse flags row t=0
  if (w == 0) {
    const u32* dp = flags + lane * 4;
    bool ok;
    do {
      u32 v0 = __hip_atomic_load(dp + 0, __ATOMIC_RELAXED, __HIP_MEMORY_SCOPE_AGENT);
      u32 v1 = __hip_atomic_load(dp + 1, __ATOMIC_RELAXED, __HIP_MEMORY_SCOPE_AGENT);
      u32 v2 = __hip_atomic_load(dp + 2, __ATOMIC_RELAXED, __HIP_MEMORY_SCOPE_AGENT);
      u32 v3 = __hip_atomic_load(dp + 3, __ATOMIC_RELAXED, __HIP_MEMORY_SCOPE_AGENT);
      ok = ((v0 & v1 & v2 & v3) == 1u);
    } while (!__all(ok));
  }
  __syncthreads();

  // block b: slab ts = b>>1, rows [r0, r0+32). LDS tile reuses the W region.
  {
    const int ts = b >> 1;
    const int r0 = (b & 1) * 32;
    float* T = (float*)smem;  // [32][1028] floats = 131584 B < SMEM_BYTES
#pragma unroll 4
    for (int it = 0; it < 16; ++it) {
      int flat = it * 512 + tid;   // 8192 chunks
      int c = flat >> 3;           // col 0..1023
      int q = flat & 7;            // row quad
      const u64* p = reinterpret_cast<const u64*>(
          zo + ((size_t)ts * NH + c) * NB + r0 + q * 4);
      u64 lo = __hip_atomic_load(p + 0, __ATOMIC_RELAXED, __HIP_MEMORY_SCOPE_AGENT);
      u64 hi = __hip_atomic_load(p + 1, __ATOMIC_RELAXED, __HIP_MEMORY_SCOPE_AGENT);
      T[(q * 4 + 0) * 1028 + c] = __builtin_bit_cast(float, (u32)lo);
      T[(q * 4 + 1) * 1028 + c] = __builtin_bit_cast(float, (u32)(lo >> 32));
      T[(q * 4 + 2) * 1028 + c] = __builtin_bit_cast(float, (u32)hi);
      T[(q * 4 + 3) * 1028 + c] = __builtin_bit_cast(float, (u32)(hi >> 32));
    }
    __syncthreads();
#pragma unroll 4
    for (int it = 0; it < 16; ++it) {
      int flat = it * 512 + tid;   // 8192 float4 writes
      int r = flat >> 8;           // 0..31
      int c4 = flat & 255;         // float4 col group
      float4 v;
      v.x = T[r * 1028 + c4 * 4 + 0];
      v.y = T[r * 1028 + c4 * 4 + 1];
      v.z = T[r * 1028 + c4 * 4 + 2];
      v.w = T[r * 1028 + c4 * 4 + 3];
      *reinterpret_cast<float4*>(
          out + ((size_t)(r0 + r) * NT + ts) * NH + c4 * 4) = v;
    }
  }
}

extern "C" void kernel_launch(void* const* d_in, const int* in_sizes, int n_in,
                              void* d_out, int out_size, void* d_ws, size_t ws_size,
                              hipStream_t stream) {
  const float* x = (const float*)d_in[0];
  const float* W = (const float*)d_in[1];
  const float* bias = (const float*)d_in[2];
  float* out = (float*)d_out;

  char* ws = (char*)d_ws;
  u16* xb = (u16*)(ws);                                  // 16 MiB
  u16* wt_blk = (u16*)(ws + 16777216);                   // 32 MiB
  u16* hseq = (u16*)(ws + 50331648);                     // 16 MiB (slab layout)
  u32* flags = (u32*)(ws + 67108864);                    // 128 KiB
  float* zo = (float*)(ws + 67239936);                   // 32 MiB (staging, col-major)

  hipMemsetAsync(hseq, 0, 256 * 512, stream);                // h_0 slabs = 0
  hipMemsetAsync(flags, 0, NT * 256 * sizeof(u32), stream);  // per-replay

  lstm_cvt_x<<<(NB * NT * NF) / (256 * 4), 256, 0, stream>>>(x, xb);
  lstm_prep_w<<<dim3(NG / 32, NK / 32), 256, 0, stream>>>(W, wt_blk);

  hipFuncSetAttribute((const void*)lstm_persist,
                      hipFuncAttributeMaxDynamicSharedMemorySize, SMEM_BYTES);

  void* args[] = {(void*)&xb, (void*)&hseq, (void*)&wt_blk, (void*)&bias,
                  (void*)&out, (void*)&flags, (void*)&zo};
  hipLaunchCooperativeKernel((void*)lstm_persist, dim3(256), dim3(512), args,
                             SMEM_BYTES, stream);
}

// Round 15
// 1036.194 us; speedup vs baseline: 2.5088x; 1.1646x over previous
//
#include <hip/hip_runtime.h>
#include <hip/hip_bf16.h>

typedef unsigned short u16;
typedef unsigned int u32;
typedef unsigned long long u64;
typedef __bf16 bf16x8 __attribute__((ext_vector_type(8)));
typedef float f32x4 __attribute__((ext_vector_type(4)));

#define NB 64
#define NT 128
#define NF 1024
#define NH 1024
#define NK 2048   // F+H
#define NG 4096   // 4H
#define NBH (NB * NH)

// flags padded to one per 64B line (u32 stride 16) to kill LLC line contention
#define FSTR 16

// LDS: W slice 128 KiB + zsx[2 buf][2][64][17] + zsh[2][64][17] + handshake
#define W_LDS_BYTES 131072
#define ZSX_BYTES (2 * 2 * 64 * 17 * 4)   // 17408
#define ZSH_BYTES (2 * 64 * 17 * 4)       // 8704
#define SMEM_BYTES (W_LDS_BYTES + ZSX_BYTES + ZSH_BYTES + 64)  // 157248 <= 163840

__device__ __forceinline__ u16 f2bf(float f) {
  unsigned u = __builtin_bit_cast(unsigned, f);
  u = (u + 0x7FFFu + ((u >> 16) & 1u)) >> 16;
  return (u16)u;
}
__device__ __forceinline__ float bf2f(u16 v) {
  unsigned u = ((unsigned)v) << 16;
  return __builtin_bit_cast(float, u);
}

// ---------------- prep: x fp32 -> bf16 ----------------
__global__ __launch_bounds__(256) void lstm_cvt_x(const float* __restrict__ x,
                                                  u16* __restrict__ xb) {
  int i = (blockIdx.x * 256 + threadIdx.x) * 4;
  float4 v = *reinterpret_cast<const float4*>(x + i);
  ushort4 o;
  o.x = f2bf(v.x); o.y = f2bf(v.y); o.z = f2bf(v.z); o.w = f2bf(v.w);
  *reinterpret_cast<ushort4*>(xb + i) = o;
}

// ---------------- prep: W [2048,4096] fp32 -> per-block LDS-image slices ----------------
// (verified R3-R14)  base idx: ((buf*2 + kh)*32 + ch)*512 + (slot*16 + brow)*8 + elem
__global__ __launch_bounds__(256) void lstm_prep_w(const float* __restrict__ W,
                                                   u16* __restrict__ wt_blk) {
  __shared__ float tile[32][33];
  int n0 = blockIdx.x * 32;
  int k0 = blockIdx.y * 32;
  int tc = threadIdx.x & 31;
  int tr = threadIdx.x >> 5;
#pragma unroll
  for (int i = 0; i < 4; ++i) {
    int k = tr + i * 8;
    tile[k][tc] = W[(size_t)(k0 + k) * NG + n0 + tc];
  }
  __syncthreads();
#pragma unroll
  for (int i = 0; i < 4; ++i) {
    int n = n0 + tr + i * 8;
    float wv = tile[tc][tr + i * 8];
    int k = k0 + tc;
    int g = n >> 10, col = n & 1023;
    int b = col >> 2, brow = g * 4 + (col & 3);
    int kh = k >> 10, ch = (k & 1023) >> 5;
    int slot = (k >> 3) & 3, elem = k & 7;
    size_t base = (size_t)b * 65536 + (size_t)(kh * 32 + ch) * 512
                + (size_t)(slot * 16 + brow) * 8 + elem;
    u16 hi = f2bf(wv);
    wt_blk[base] = hi;
    wt_blk[base + 32768] = f2bf(wv - bf2f(hi));
  }
}

// x A-pass: 4 M-frags (rows i*16+arow), K=256 slice, hi+lo MFMA, 2-stage pipeline.
__device__ __forceinline__ void mfma_pass(const u16* __restrict__ a0, size_t rstride,
                                          const u16* __restrict__ Wl, int khalf,
                                          int kq, int lane, f32x4 acc[4]) {
  bf16x8 pf[4], qf[4];
#pragma unroll
  for (int i = 0; i < 4; ++i)
    pf[i] = *reinterpret_cast<const bf16x8*>(a0 + (size_t)i * 16 * rstride);
#pragma unroll
  for (int cc = 0; cc < 8; ++cc) {
    if (cc < 7) {
#pragma unroll
      for (int i = 0; i < 4; ++i)
        qf[i] = *reinterpret_cast<const bf16x8*>(a0 + (size_t)i * 16 * rstride + (cc + 1) * 32);
    }
    const int ch = kq * 8 + cc;
    const bf16x8 wh = *reinterpret_cast<const bf16x8*>(
        Wl + (size_t)(khalf * 32 + ch) * 512 + lane * 8);
    const bf16x8 wl2 = *reinterpret_cast<const bf16x8*>(
        Wl + (size_t)(64 + khalf * 32 + ch) * 512 + lane * 8);
#pragma unroll
    for (int i = 0; i < 4; ++i)
      acc[i] = __builtin_amdgcn_mfma_f32_16x16x32_bf16(pf[i], wh, acc[i], 0, 0, 0);
#pragma unroll
    for (int i = 0; i < 4; ++i)
      acc[i] = __builtin_amdgcn_mfma_f32_16x16x32_bf16(pf[i], wl2, acc[i], 0, 0, 0);
#pragma unroll
    for (int i = 0; i < 4; ++i) pf[i] = qf[i];
  }
}

// ---------------- persistent LSTM (R14 + line-padded, paced flag polls) ----------
// hseq layout: [t][producer block pb][row 0..64][4 cols] -- 512 B contiguous
// per block (coalesced publish, 8 LLC lines). Flags: ONE PER 64B LINE (stride
// 16 u32) so each line has 256 pollers instead of 4096; polls paced with
// s_sleep(1) on miss. Consumer: lane's bf16x8 = two u64 from adjacent slabs.
__global__ __launch_bounds__(512) void lstm_persist(
    const u16* __restrict__ xb, u16* __restrict__ hseq,
    const u16* __restrict__ wt_blk, const float* __restrict__ bias,
    float* __restrict__ out, u32* __restrict__ flags,
    float* __restrict__ zo) {
  extern __shared__ char smem[];
  u16* Wl = (u16*)smem;
  float (*zsx)[2][64][17] = (float(*)[2][64][17])(smem + W_LDS_BYTES);
  float (*zsh)[64][17] = (float(*)[64][17])(smem + W_LDS_BYTES + ZSX_BYTES);
  volatile u32* hsflag = (volatile u32*)(smem + W_LDS_BYTES + ZSX_BYTES + ZSH_BYTES);

  const int b = blockIdx.x;
  const int tid = threadIdx.x;
  const int lane = tid & 63;
  const int w = tid >> 6;
  const bool is_x = (w < 4);
  const int kq = w & 3;

  // ---- load W slice (128 KiB) into LDS ----
  {
    const u16* src = wt_blk + (size_t)b * 65536;
#pragma unroll
    for (int it = 0; it < 16; ++it) {
      uint4 v = *reinterpret_cast<const uint4*>(src + (size_t)it * 4096 + tid * 8);
      *reinterpret_cast<uint4*>(Wl + (size_t)it * 4096 + tid * 8) = v;
    }
  }
  // zero zsh (t=0 has no h contribution)
  for (int i = tid; i < 2 * 64 * 17; i += 512) ((float*)zsh)[i] = 0.f;
  if (tid == 0) hsflag[0] = 0u;

  const int arow = lane & 15;
  const int kfr = 8 * (lane >> 4);
  const int kbase = kq * 256 + kfr;
  const int zn = lane & 15;
  const int mg = (lane >> 4) * 4;

  // pointwise ownership: tid<128 owns (prow, 2 cols)
  const int prow = tid >> 1;
  const int pc = (tid & 1) * 2;
  const int gc0 = b * 4 + pc;
  float bz[2][4];
  float creg[2] = {0.f, 0.f};
  if (tid < 128) {
#pragma unroll
    for (int j = 0; j < 2; ++j) {
      bz[j][0] = bias[gc0 + j];
      bz[j][1] = bias[NH + gc0 + j];
      bz[j][2] = bias[2 * NH + gc0 + j];
      bz[j][3] = bias[3 * NH + gc0 + j];
    }
  }
  __syncthreads();

  // ---- prologue: x-waves fill zsx[0] = zx(0) ----
  {
    f32x4 acc[4] = {};
    if (is_x) {
      const u16* a0 = xb + ((size_t)arow * NT + 0) * NF + kbase;
      mfma_pass(a0, (size_t)NT * NF, Wl, 0, kq, lane, acc);
      if (w < 2) {
#pragma unroll
        for (int i = 0; i < 4; ++i)
#pragma unroll
          for (int r = 0; r < 4; ++r) zsx[0][w][i * 16 + mg + r][zn] = acc[i][r];
      }
    }
    __syncthreads();
    if (is_x && w >= 2) {
#pragma unroll
      for (int i = 0; i < 4; ++i)
#pragma unroll
        for (int r = 0; r < 4; ++r) zsx[0][w - 2][i * 16 + mg + r][zn] += acc[i][r];
    }
    __syncthreads();
  }

#pragma unroll 1
  for (int t = 0; t < NT; ++t) {
    const int cb = t & 1;        // zsx buffer consumed this step
    const int nb = (t + 1) & 1;  // zsx buffer filled this step
    f32x4 acc[4] = {};

    if (is_x) {
      if (t < NT - 1) {
        const u16* a0 = xb + ((size_t)arow * NT + (t + 1)) * NF + kbase;
        mfma_pass(a0, (size_t)NT * NF, Wl, 0, kq, lane, acc);
      }
    } else {
      if (t > 0) {
        // dataflow poll (line-padded flags, paced): producers [64kq, 64kq+64)
        const u32* fp = flags + ((size_t)t * 256 + kq * 64 + lane) * FSTR;
        u32 v = __hip_atomic_load(fp, __ATOMIC_RELAXED, __HIP_MEMORY_SCOPE_AGENT);
        while (!__all(v != 0)) {
          __builtin_amdgcn_s_sleep(1);
          v = __hip_atomic_load(fp, __ATOMIC_RELAXED, __HIP_MEMORY_SCOPE_AGENT);
        }

        // ---- slab-layout h-GEMM: lane's bf16x8 = u64 pair from slabs ----
        const u64* hb = reinterpret_cast<const u64*>(hseq) + (size_t)t * (256 * 64);
        const int sbase = kq * 64 + 2 * (lane >> 4);
        u64 plo[4], phi[4], qlo[4], qhi[4];
#pragma unroll
        for (int i = 0; i < 4; ++i) {
          plo[i] = hb[(size_t)sbase * 64 + arow + 16 * i];
          phi[i] = hb[(size_t)(sbase + 1) * 64 + arow + 16 * i];
        }
        __builtin_amdgcn_s_setprio(1);
#pragma unroll
        for (int cc = 0; cc < 8; ++cc) {
          if (cc < 7) {
            const int s = sbase + (cc + 1) * 8;
#pragma unroll
            for (int i = 0; i < 4; ++i) {
              qlo[i] = hb[(size_t)s * 64 + arow + 16 * i];
              qhi[i] = hb[(size_t)(s + 1) * 64 + arow + 16 * i];
            }
          }
          const int ch = kq * 8 + cc;
          const bf16x8 wh = *reinterpret_cast<const bf16x8*>(
              Wl + (size_t)(32 + ch) * 512 + lane * 8);             // kh=1 hi
          const bf16x8 wlo = *reinterpret_cast<const bf16x8*>(
              Wl + (size_t)(96 + ch) * 512 + lane * 8);             // kh=1 lo
#pragma unroll
          for (int i = 0; i < 4; ++i) {
            union HU { u64 q[2]; bf16x8 f; } u;
            u.q[0] = plo[i];
            u.q[1] = phi[i];
            acc[i] = __builtin_amdgcn_mfma_f32_16x16x32_bf16(u.f, wh, acc[i], 0, 0, 0);
            acc[i] = __builtin_amdgcn_mfma_f32_16x16x32_bf16(u.f, wlo, acc[i], 0, 0, 0);
          }
#pragma unroll
          for (int i = 0; i < 4; ++i) { plo[i] = qlo[i]; phi[i] = qhi[i]; }
        }
        __builtin_amdgcn_s_setprio(0);
      }
    }

    // ---- write phase ----
    if (is_x) {
      if (w < 2 && t < NT - 1) {
#pragma unroll
        for (int i = 0; i < 4; ++i)
#pragma unroll
          for (int r = 0; r < 4; ++r) zsx[nb][w][i * 16 + mg + r][zn] = acc[i][r];
      }
    } else {
      if (w < 6 && t > 0) {
#pragma unroll
        for (int i = 0; i < 4; ++i)
#pragma unroll
          for (int r = 0; r < 4; ++r) zsh[w - 4][i * 16 + mg + r][zn] = acc[i][r];
      }
    }
    __syncthreads();
    // ---- add phase ----
    if (is_x) {
      if (w >= 2 && t < NT - 1) {
#pragma unroll
        for (int i = 0; i < 4; ++i)
#pragma unroll
          for (int r = 0; r < 4; ++r) zsx[nb][w - 2][i * 16 + mg + r][zn] += acc[i][r];
      }
    } else {
      if (w >= 6 && t > 0) {
#pragma unroll
        for (int i = 0; i < 4; ++i)
#pragma unroll
          for (int r = 0; r < 4; ++r) zsh[w - 6][i * 16 + mg + r][zn] += acc[i][r];
      }
    }
    __syncthreads();

    // ---- fused pointwise + coalesced h publish + staged output ----
    if (tid < 128) {
      float hn[2];
#pragma unroll
      for (int jj = 0; jj < 2; ++jj) {
        const int col = pc + jj;
        const float zi = zsx[cb][0][prow][col]      + zsx[cb][1][prow][col]      + zsh[0][prow][col]      + zsh[1][prow][col]      + bz[jj][0];
        const float zj = zsx[cb][0][prow][4 + col]  + zsx[cb][1][prow][4 + col]  + zsh[0][prow][4 + col]  + zsh[1][prow][4 + col]  + bz[jj][1];
        const float zf = zsx[cb][0][prow][8 + col]  + zsx[cb][1][prow][8 + col]  + zsh[0][prow][8 + col]  + zsh[1][prow][8 + col]  + bz[jj][2];
        const float zo4 = zsx[cb][0][prow][12 + col] + zsx[cb][1][prow][12 + col] + zsh[0][prow][12 + col] + zsh[1][prow][12 + col] + bz[jj][3];
        const float si = 1.f / (1.f + __expf(-zi));
        const float tj = tanhf(zj);
        const float sf = 1.f / (1.f + __expf(-(zf + 1.0f)));  // FORGET_BIAS = 1
        const float so = 1.f / (1.f + __expf(-zo4));
        const float cn = creg[jj] * sf + si * tj;
        hn[jj] = tanhf(cn) * so;
        creg[jj] = cn;
      }
      if (t < NT - 1) {
        // h publish: SLAB layout -> 128 consecutive u32 = 512 B, 8 LLC lines
        u32 hv = (u32)f2bf(hn[0]) | ((u32)f2bf(hn[1]) << 16);
        u32* hp = reinterpret_cast<u32*>(hseq)
                + ((size_t)(t + 1) * 256 + b) * 128 + prow * 2 + (pc >> 1);
        __hip_atomic_store(hp, hv, __ATOMIC_RELAXED, __HIP_MEMORY_SCOPE_AGENT);
        asm volatile("s_waitcnt vmcnt(0)" ::: "memory");  // 8-line ack
        if (tid == 64) hsflag[0] = (u32)(t + 1);          // wave 1 drained
        if (tid == 0) {
          while (hsflag[0] != (u32)(t + 1)) {}            // wait wave 1
          __hip_atomic_store(&flags[((size_t)(t + 1) * 256 + b) * FSTR], 1u,
                             __ATOMIC_RELAXED, __HIP_MEMORY_SCOPE_AGENT);
        }
      }
      // staged output: column-major zo[t][col][row], after the flag publish
#pragma unroll
      for (int jj = 0; jj < 2; ++jj) {
        __hip_atomic_store(
            reinterpret_cast<u32*>(zo + ((size_t)t * NH + gc0 + jj) * NB + prow),
            __builtin_bit_cast(u32, hn[jj]),
            __ATOMIC_RELAXED, __HIP_MEMORY_SCOPE_AGENT);
      }
    }
    // h-waves proceed to poll step t+1 while waves 0-1 finish the tail
  }

  // ================= final: grid rendezvous, then zo -> out transpose =========
  __syncthreads();
  asm volatile("s_waitcnt vmcnt(0)" ::: "memory");  // all zo stores at LLC
  if (tid == 0)
    __hip_atomic_store(&flags[(size_t)b * FSTR], 1u, __ATOMIC_RELAXED,
                       __HIP_MEMORY_SCOPE_AGENT);  // reuse flags row t=0
  if (w == 0) {
    bool ok;
    do {
      u32 v0 = __hip_atomic_load(flags + (size_t)(lane * 4 + 0) * FSTR, __ATOMIC_RELAXED, __HIP_MEMORY_SCOPE_AGENT);
      u32 v1 = __hip_atomic_load(flags + (size_t)(lane * 4 + 1) * FSTR, __ATOMIC_RELAXED, __HIP_MEMORY_SCOPE_AGENT);
      u32 v2 = __hip_atomic_load(flags + (size_t)(lane * 4 + 2) * FSTR, __ATOMIC_RELAXED, __HIP_MEMORY_SCOPE_AGENT);
      u32 v3 = __hip_atomic_load(flags + (size_t)(lane * 4 + 3) * FSTR, __ATOMIC_RELAXED, __HIP_MEMORY_SCOPE_AGENT);
      ok = ((v0 & v1 & v2 & v3) == 1u);
      if (!__all(ok)) __builtin_amdgcn_s_sleep(1);
    } while (!__all(ok));
  }
  __syncthreads();

  // block b: slab ts = b>>1, rows [r0, r0+32). LDS tile reuses the W region.
  {
    const int ts = b >> 1;
    const int r0 = (b & 1) * 32;
    float* T = (float*)smem;  // [32][1028] floats = 131584 B < SMEM_BYTES
#pragma unroll 4
    for (int it = 0; it < 16; ++it) {
      int flat = it * 512 + tid;   // 8192 chunks
      int c = flat >> 3;           // col 0..1023
      int q = flat & 7;            // row quad
      const u64* p = reinterpret_cast<const u64*>(
          zo + ((size_t)ts * NH + c) * NB + r0 + q * 4);
      u64 lo = __hip_atomic_load(p + 0, __ATOMIC_RELAXED, __HIP_MEMORY_SCOPE_AGENT);
      u64 hi = __hip_atomic_load(p + 1, __ATOMIC_RELAXED, __HIP_MEMORY_SCOPE_AGENT);
      T[(q * 4 + 0) * 1028 + c] = __builtin_bit_cast(float, (u32)lo);
      T[(q * 4 + 1) * 1028 + c] = __builtin_bit_cast(float, (u32)(lo >> 32));
      T[(q * 4 + 2) * 1028 + c] = __builtin_bit_cast(float, (u32)hi);
      T[(q * 4 + 3) * 1028 + c] = __builtin_bit_cast(float, (u32)(hi >> 32));
    }
    __syncthreads();
#pragma unroll 4
    for (int it = 0; it < 16; ++it) {
      int flat = it * 512 + tid;   // 8192 float4 writes
      int r = flat >> 8;           // 0..31
      int c4 = flat & 255;         // float4 col group
      float4 v;
      v.x = T[r * 1028 + c4 * 4 + 0];
      v.y = T[r * 1028 + c4 * 4 + 1];
      v.z = T[r * 1028 + c4 * 4 + 2];
      v.w = T[r * 1028 + c4 * 4 + 3];
      *reinterpret_cast<float4*>(
          out + ((size_t)(r0 + r) * NT + ts) * NH + c4 * 4) = v;
    }
  }
}

extern "C" void kernel_launch(void* const* d_in, const int* in_sizes, int n_in,
                              void* d_out, int out_size, void* d_ws, size_t ws_size,
                              hipStream_t stream) {
  const float* x = (const float*)d_in[0];
  const float* W = (const float*)d_in[1];
  const float* bias = (const float*)d_in[2];
  float* out = (float*)d_out;

  char* ws = (char*)d_ws;
  u16* xb = (u16*)(ws);                                  // 16 MiB
  u16* wt_blk = (u16*)(ws + 16777216);                   // 32 MiB
  u16* hseq = (u16*)(ws + 50331648);                     // 16 MiB (slab layout)
  u32* flags = (u32*)(ws + 67108864);                    // 2 MiB (line-padded)
  float* zo = (float*)(ws + 69206016);                   // 32 MiB (staging, col-major)

  hipMemsetAsync(hseq, 0, 256 * 512, stream);                       // h_0 slabs = 0
  hipMemsetAsync(flags, 0, (size_t)NT * 256 * FSTR * 4, stream);    // per-replay

  lstm_cvt_x<<<(NB * NT * NF) / (256 * 4), 256, 0, stream>>>(x, xb);
  lstm_prep_w<<<dim3(NG / 32, NK / 32), 256, 0, stream>>>(W, wt_blk);

  hipFuncSetAttribute((const void*)lstm_persist,
                      hipFuncAttributeMaxDynamicSharedMemorySize, SMEM_BYTES);

  void* args[] = {(void*)&xb, (void*)&hseq, (void*)&wt_blk, (void*)&bias,
                  (void*)&out, (void*)&flags, (void*)&zo};
  hipLaunchCooperativeKernel((void*)lstm_persist, dim3(256), dim3(512), args,
                             SMEM_BYTES, stream);
}